// Round 21
// baseline (35.950 us; speedup 1.0000x reference)
//
#include <hip/hip_runtime.h>
#include <math.h>

#define B_ 4
#define T_ 512
#define C_ 128
#define HS_ 64

typedef float f4 __attribute__((ext_vector_type(4)));
typedef float f2 __attribute__((ext_vector_type(2)));

// scale = C^-0.5
#define SCALE_ 0.08838834764831845f

static __device__ __forceinline__ f2 relu2(f2 v) {
    v.x = fmaxf(v.x, 0.f);
    v.y = fmaxf(v.y, 0.f);
    return v;
}

// ---------------------------------------------------------------------------
// Kernel 1: prep.  x1 = x + pos_emb;  Aq = x1@W1q + b1;  AkT = (x1@W1k)^T;
// V = x@Wv.  256 blocks x 640 threads, block = 8 rows.
// NEW (R21): all intermediate stores are NONTEMPORAL. Rationale: R16/R17
// within-probe measurement shows fused's first pass costs 24.6us vs 13.8us
// warm — ~10.8us of cold penalty. prep's normal stores leave Aq/AkT/V dirty
// in the WRITER XCD's L2; every fused block reads a slab spanning all prep
// blocks' rows, so first reads are cross-XCD dirty-line snoops (slow
// coherence path). nt stores bypass the local L2 -> readers stream clean
// lines from L3/HBM (2.5MB ~ 0.4us of BW) into their own L2.
// ---------------------------------------------------------------------------
__global__ __launch_bounds__(640) void k_prep(
    const float* __restrict__ x, const float* __restrict__ pos,
    const float* __restrict__ W1, const float* __restrict__ b1,
    const float* __restrict__ Wv,
    float* __restrict__ Aq, float* __restrict__ AkT, float* __restrict__ V)
{
    __shared__ float x1s[8 * 132];
    __shared__ float xs[8 * 132];
    const int t = threadIdx.x;
    const int row0 = blockIdx.x * 8;  // over B*T = 2048

    if (t < 256) {
        int r = t >> 5, cq = t & 31;
        int gr = row0 + r;
        f4 xv = *(const f4*)(x + gr * 128 + cq * 4);
        f4 pv = *(const f4*)(pos + (gr & 511) * 128 + cq * 4);
        *(f4*)&xs[r * 132 + cq * 4] = xv;
        *(f4*)&x1s[r * 132 + cq * 4] = xv + pv;
    }
    __syncthreads();

    const int q = t >> 3;   // 0..79 col-quad
    const int r = t & 7;    // row in tile

    const float* wbase;
    int wstr, col0;
    const float* xb;
    f4 binit = {0.f, 0.f, 0.f, 0.f};
    if (q < 32) {
        col0 = q * 4;
        wbase = W1 + 128 * 128 + col0;  // W1q rows (c-major)
        wstr = 128;
        xb = x1s;
        binit = *(const f4*)(b1 + col0);
    } else if (q < 64) {
        col0 = (q - 32) * 4;
        wbase = W1 + col0;  // W1k rows
        wstr = 128;
        xb = x1s;
    } else {
        col0 = (q - 64) * 4;
        wbase = Wv + col0;
        wstr = 64;
        xb = xs;
    }

    f4 acc = binit;
    const float* xr = xb + r * 132;
#pragma unroll 8
    for (int c = 0; c < 128; ++c) {
        f4 w = *(const f4*)(wbase + c * wstr);
        acc += xr[c] * w;
    }

    const int gr = row0 + r;
    if (q < 32) {
        __builtin_nontemporal_store(acc, (f4*)(Aq + (size_t)gr * 128 + col0));
    } else if (q < 64) {
        const int bb = gr >> 9, j = gr & 511;
        float* base = AkT + ((size_t)bb * 128 + col0) * 512 + j;
        __builtin_nontemporal_store(acc.x, base);
        __builtin_nontemporal_store(acc.y, base + 512);
        __builtin_nontemporal_store(acc.z, base + 1024);
        __builtin_nontemporal_store(acc.w, base + 1536);
    } else {
        __builtin_nontemporal_store(acc, (f4*)(V + (size_t)gr * 64 + col0));
    }
}

// ---------------------------------------------------------------------------
// Kernel 2: fused wei + causal softmax + PV, ROW QUAD, balanced chunks.
// (round 15 verbatim — the measured champion; R20's packed/interleave
// variations were null-to-negative and are reverted.)
// ---------------------------------------------------------------------------
__global__ __launch_bounds__(256, 4) void k_fused(
    const float* __restrict__ Aq, const float* __restrict__ AkT,
    const float* __restrict__ Vv, const float* __restrict__ W2,
    float* __restrict__ out)
{
    __shared__ float pbuf[4][4][128];
    __shared__ float accs[4][4][64];
    __shared__ float mls[4][4][2];

    const int t = threadIdx.x;
    const int bx = blockIdx.x;         // 0..511
    const int b = bx & 3;
    const int g = 127 - (bx >> 2);     // descending: heavy quads first
    const int r0 = g * 4;
    const int w = t >> 6, lane = t & 63;

    const int nj = r0 + 4;                      // live j count for this quad
    const int cj = ((nj + 7) >> 3) << 1;        // per-wave chunk, even, <=128
    const int jstart = w * cj;
    const int jend = min(jstart + cj, nj);
    const int jA = jstart + lane * 2;

    float m0 = -1e30f, m1 = -1e30f, m2 = -1e30f, m3 = -1e30f;
    float l0 = 0.f, l1 = 0.f, l2 = 0.f, l3 = 0.f;
    float a0 = 0.f, a1 = 0.f, a2 = 0.f, a3 = 0.f;

    if (jstart < jend) {
        const float* aq0 = Aq + (size_t)(b * 512 + r0) * 128;
        const float* aq1 = aq0 + 128;
        const float* aq2 = aq1 + 128;
        const float* aq3 = aq2 + 128;
        const float* akt = AkT + (size_t)b * 65536 + jA;  // jA <= 510 always

        f2 s0a = {0,0}, s0b = {0,0}, s1a = {0,0}, s1b = {0,0};
        f2 s2a = {0,0}, s2b = {0,0}, s3a = {0,0}, s3b = {0,0};
#pragma unroll 4
        for (int c = 0; c < 128; c += 2) {
            const f2 k0 = *(const f2*)(akt + (size_t)c * 512);
            const f2 k1 = *(const f2*)(akt + (size_t)(c + 1) * 512);
            const float w0 = W2[c], w1 = W2[c + 1];
            s0a += relu2(k0 + aq0[c]) * w0;  s0b += relu2(k1 + aq0[c + 1]) * w1;
            s1a += relu2(k0 + aq1[c]) * w0;  s1b += relu2(k1 + aq1[c + 1]) * w1;
            s2a += relu2(k0 + aq2[c]) * w0;  s2b += relu2(k1 + aq2[c + 1]) * w1;
            s3a += relu2(k0 + aq3[c]) * w0;  s3b += relu2(k1 + aq3[c + 1]) * w1;
        }

#define FINROW(R, SA, SB, MD, LD)                                        \
        {                                                                \
            const int rr_ = r0 + (R);                                    \
            const int jlim_ = min(jend - 1, rr_);                        \
            f2 sv = (SA + SB) * SCALE_;                                  \
            float sx = (jA     <= jlim_) ? sv.x : -1e30f;                \
            float sy = (jA + 1 <= jlim_) ? sv.y : -1e30f;                \
            float mx = fmaxf(sx, sy);                                    \
            _Pragma("unroll")                                            \
            for (int off = 1; off < 64; off <<= 1)                       \
                mx = fmaxf(mx, __shfl_xor(mx, off));                     \
            const bool live_ = (jstart <= rr_);                          \
            const float px = live_ ? __expf(sx - mx) : 0.f;              \
            const float py = live_ ? __expf(sy - mx) : 0.f;              \
            f2 pp = {px, py};                                            \
            *(f2*)&pbuf[w][R][lane * 2] = pp;                            \
            float ls = px + py;                                          \
            _Pragma("unroll")                                            \
            for (int off = 1; off < 64; off <<= 1)                       \
                ls += __shfl_xor(ls, off);                               \
            MD = live_ ? mx : -1e30f;                                    \
            LD = ls;                                                     \
        }
        FINROW(0, s0a, s0b, m0, l0)
        FINROW(1, s1a, s1b, m1, l1)
        FINROW(2, s2a, s2b, m2, l2)
        FINROW(3, s3a, s3b, m3, l3)
#undef FINROW

        // ---- PV over the chunk; lane = h; V loads shared by 4 rows ----
        const float* vt = Vv + ((size_t)b * 512 + jstart) * 64 + lane;
        const int q4max = (jend - jstart + 3) >> 2;
        for (int q4 = 0; q4 < q4max; ++q4) {
            const f4 p0 = *(const f4*)&pbuf[w][0][q4 * 4];
            const f4 p1 = *(const f4*)&pbuf[w][1][q4 * 4];
            const f4 p2 = *(const f4*)&pbuf[w][2][q4 * 4];
            const f4 p3 = *(const f4*)&pbuf[w][3][q4 * 4];
            const float v0 = vt[(q4 * 4 + 0) * 64];
            const float v1 = vt[(q4 * 4 + 1) * 64];
            const float v2 = vt[(q4 * 4 + 2) * 64];
            const float v3 = vt[(q4 * 4 + 3) * 64];
            a0 += p0.x * v0 + p0.y * v1 + p0.z * v2 + p0.w * v3;
            a1 += p1.x * v0 + p1.y * v1 + p1.z * v2 + p1.w * v3;
            a2 += p2.x * v0 + p2.y * v1 + p2.z * v2 + p2.w * v3;
            a3 += p3.x * v0 + p3.y * v1 + p3.z * v2 + p3.w * v3;
        }
    }

    // ---- partials to LDS; in-block flash merge ----
    accs[w][0][lane] = a0;
    accs[w][1][lane] = a1;
    accs[w][2][lane] = a2;
    accs[w][3][lane] = a3;
    if (lane == 0) {
        mls[w][0][0] = m0; mls[w][0][1] = l0;
        mls[w][1][0] = m1; mls[w][1][1] = l1;
        mls[w][2][0] = m2; mls[w][2][1] = l2;
        mls[w][3][0] = m3; mls[w][3][1] = l3;
    }
    __syncthreads();

    // wave w merges row r0 + w over all 4 wave partials
    const int rr = r0 + w;
    float ms = -1e30f;
#pragma unroll
    for (int ww = 0; ww < 4; ++ww) ms = fmaxf(ms, mls[ww][w][0]);
    float num = 0.f, den = 0.f;
#pragma unroll
    for (int ww = 0; ww < 4; ++ww) {
        const float e = __expf(mls[ww][w][0] - ms);
        den += mls[ww][w][1] * e;
        num += accs[ww][w][lane] * e;
    }
    out[(size_t)(b * 512 + rr) * 64 + lane] = num / den;
}

// ---------------------------------------------------------------------------
extern "C" void kernel_launch(void* const* d_in, const int* in_sizes, int n_in,
                              void* d_out, int out_size, void* d_ws, size_t ws_size,
                              hipStream_t stream)
{
    const float* x   = (const float*)d_in[0];
    const float* pos = (const float*)d_in[1];
    const float* W1  = (const float*)d_in[2];
    const float* b1  = (const float*)d_in[3];
    const float* W2  = (const float*)d_in[4];
    const float* b2  = (const float*)d_in[5];  (void)b2;  // cancels in softmax
    const float* Wv  = (const float*)d_in[6];
    float* out = (float*)d_out;
    float* ws = (float*)d_ws;

    float* Aq  = ws;                 // B*T*C = 262144
    float* AkT = ws + 262144;        // B*C*T = 262144 (transposed)
    float* V   = ws + 524288;        // B*T*HS = 131072

    k_prep<<<dim3(256), dim3(640), 0, stream>>>(x, pos, W1, b1, Wv, Aq, AkT, V);
    k_fused<<<dim3(512), dim3(256), 0, stream>>>(Aq, AkT, V, W2, out);
}

// Round 22
// 33.630 us; speedup vs baseline: 1.0690x; 1.0690x over previous
//
#include <hip/hip_runtime.h>
#include <math.h>

#define B_ 4
#define T_ 512
#define C_ 128
#define HS_ 64

typedef float f4 __attribute__((ext_vector_type(4)));
typedef float f2 __attribute__((ext_vector_type(2)));

// scale = C^-0.5
#define SCALE_ 0.08838834764831845f

static __device__ __forceinline__ f2 relu2(f2 v) {
    v.x = fmaxf(v.x, 0.f);
    v.y = fmaxf(v.y, 0.f);
    return v;
}

// ---------------------------------------------------------------------------
// SESSION CHAMPION (round 15, 33.28us) — restored verbatim.
// Structure: 2 kernels.
//  k_prep: x1 = x+pos; Aq = x1@W1q+b1; AkT = (x1@W1k)^T (scatter); V = x@Wv.
//  k_fused: per (batch, row-quad) block, 4 waves with BALANCED j-chunks;
//    shuffle-free S c-loop on transposed Ak (f2 coalesced), per-chunk
//    softmax, PV with 4-way-shared V loads, in-block flash merge.
// Floor analysis (R16-R21): ~5us VALU + ~14us fused @55% VALUBusy (rest =
// L2 latency on the global triangular read) + ~9us prep+launch. All tested
// levers (traffic, balance, prefetch, packing, nt, coop, occupancy) null.
// ---------------------------------------------------------------------------
__global__ __launch_bounds__(640) void k_prep(
    const float* __restrict__ x, const float* __restrict__ pos,
    const float* __restrict__ W1, const float* __restrict__ b1,
    const float* __restrict__ Wv,
    float* __restrict__ Aq, float* __restrict__ AkT, float* __restrict__ V)
{
    __shared__ float x1s[8 * 132];
    __shared__ float xs[8 * 132];
    const int t = threadIdx.x;
    const int row0 = blockIdx.x * 8;  // over B*T = 2048

    if (t < 256) {
        int r = t >> 5, cq = t & 31;
        int gr = row0 + r;
        f4 xv = *(const f4*)(x + gr * 128 + cq * 4);
        f4 pv = *(const f4*)(pos + (gr & 511) * 128 + cq * 4);
        *(f4*)&xs[r * 132 + cq * 4] = xv;
        *(f4*)&x1s[r * 132 + cq * 4] = xv + pv;
    }
    __syncthreads();

    const int q = t >> 3;   // 0..79 col-quad
    const int r = t & 7;    // row in tile

    const float* wbase;
    int wstr, col0;
    const float* xb;
    f4 binit = {0.f, 0.f, 0.f, 0.f};
    if (q < 32) {
        col0 = q * 4;
        wbase = W1 + 128 * 128 + col0;  // W1q rows (c-major)
        wstr = 128;
        xb = x1s;
        binit = *(const f4*)(b1 + col0);
    } else if (q < 64) {
        col0 = (q - 32) * 4;
        wbase = W1 + col0;  // W1k rows
        wstr = 128;
        xb = x1s;
    } else {
        col0 = (q - 64) * 4;
        wbase = Wv + col0;
        wstr = 64;
        xb = xs;
    }

    f4 acc = binit;
    const float* xr = xb + r * 132;
#pragma unroll 8
    for (int c = 0; c < 128; ++c) {
        f4 w = *(const f4*)(wbase + c * wstr);
        acc += xr[c] * w;
    }

    const int gr = row0 + r;
    if (q < 32) {
        *(f4*)(Aq + (size_t)gr * 128 + col0) = acc;
    } else if (q < 64) {
        const int bb = gr >> 9, j = gr & 511;
        float* base = AkT + ((size_t)bb * 128 + col0) * 512 + j;
        base[0]    = acc.x;
        base[512]  = acc.y;
        base[1024] = acc.z;
        base[1536] = acc.w;
    } else {
        *(f4*)(V + (size_t)gr * 64 + col0) = acc;
    }
}

// ---------------------------------------------------------------------------
// Kernel 2: fused wei + causal softmax + PV, ROW QUAD, balanced chunks.
// ---------------------------------------------------------------------------
__global__ __launch_bounds__(256, 4) void k_fused(
    const float* __restrict__ Aq, const float* __restrict__ AkT,
    const float* __restrict__ Vv, const float* __restrict__ W2,
    float* __restrict__ out)
{
    __shared__ float pbuf[4][4][128];
    __shared__ float accs[4][4][64];
    __shared__ float mls[4][4][2];

    const int t = threadIdx.x;
    const int bx = blockIdx.x;         // 0..511
    const int b = bx & 3;
    const int g = 127 - (bx >> 2);     // descending: heavy quads first
    const int r0 = g * 4;
    const int w = t >> 6, lane = t & 63;

    const int nj = r0 + 4;                      // live j count for this quad
    const int cj = ((nj + 7) >> 3) << 1;        // per-wave chunk, even, <=128
    const int jstart = w * cj;
    const int jend = min(jstart + cj, nj);
    const int jA = jstart + lane * 2;

    float m0 = -1e30f, m1 = -1e30f, m2 = -1e30f, m3 = -1e30f;
    float l0 = 0.f, l1 = 0.f, l2 = 0.f, l3 = 0.f;
    float a0 = 0.f, a1 = 0.f, a2 = 0.f, a3 = 0.f;

    if (jstart < jend) {
        const float* aq0 = Aq + (size_t)(b * 512 + r0) * 128;
        const float* aq1 = aq0 + 128;
        const float* aq2 = aq1 + 128;
        const float* aq3 = aq2 + 128;
        const float* akt = AkT + (size_t)b * 65536 + jA;  // jA <= 510 always

        f2 s0a = {0,0}, s0b = {0,0}, s1a = {0,0}, s1b = {0,0};
        f2 s2a = {0,0}, s2b = {0,0}, s3a = {0,0}, s3b = {0,0};
#pragma unroll 4
        for (int c = 0; c < 128; c += 2) {
            const f2 k0 = *(const f2*)(akt + (size_t)c * 512);
            const f2 k1 = *(const f2*)(akt + (size_t)(c + 1) * 512);
            const float w0 = W2[c], w1 = W2[c + 1];
            s0a += relu2(k0 + aq0[c]) * w0;  s0b += relu2(k1 + aq0[c + 1]) * w1;
            s1a += relu2(k0 + aq1[c]) * w0;  s1b += relu2(k1 + aq1[c + 1]) * w1;
            s2a += relu2(k0 + aq2[c]) * w0;  s2b += relu2(k1 + aq2[c + 1]) * w1;
            s3a += relu2(k0 + aq3[c]) * w0;  s3b += relu2(k1 + aq3[c + 1]) * w1;
        }

#define FINROW(R, SA, SB, MD, LD)                                        \
        {                                                                \
            const int rr_ = r0 + (R);                                    \
            const int jlim_ = min(jend - 1, rr_);                        \
            f2 sv = (SA + SB) * SCALE_;                                  \
            float sx = (jA     <= jlim_) ? sv.x : -1e30f;                \
            float sy = (jA + 1 <= jlim_) ? sv.y : -1e30f;                \
            float mx = fmaxf(sx, sy);                                    \
            _Pragma("unroll")                                            \
            for (int off = 1; off < 64; off <<= 1)                       \
                mx = fmaxf(mx, __shfl_xor(mx, off));                     \
            const bool live_ = (jstart <= rr_);                          \
            const float px = live_ ? __expf(sx - mx) : 0.f;              \
            const float py = live_ ? __expf(sy - mx) : 0.f;              \
            f2 pp = {px, py};                                            \
            *(f2*)&pbuf[w][R][lane * 2] = pp;                            \
            float ls = px + py;                                          \
            _Pragma("unroll")                                            \
            for (int off = 1; off < 64; off <<= 1)                       \
                ls += __shfl_xor(ls, off);                               \
            MD = live_ ? mx : -1e30f;                                    \
            LD = ls;                                                     \
        }
        FINROW(0, s0a, s0b, m0, l0)
        FINROW(1, s1a, s1b, m1, l1)
        FINROW(2, s2a, s2b, m2, l2)
        FINROW(3, s3a, s3b, m3, l3)
#undef FINROW

        // ---- PV over the chunk; lane = h; V loads shared by 4 rows ----
        const float* vt = Vv + ((size_t)b * 512 + jstart) * 64 + lane;
        const int q4max = (jend - jstart + 3) >> 2;
        for (int q4 = 0; q4 < q4max; ++q4) {
            const f4 p0 = *(const f4*)&pbuf[w][0][q4 * 4];
            const f4 p1 = *(const f4*)&pbuf[w][1][q4 * 4];
            const f4 p2 = *(const f4*)&pbuf[w][2][q4 * 4];
            const f4 p3 = *(const f4*)&pbuf[w][3][q4 * 4];
            const float v0 = vt[(q4 * 4 + 0) * 64];
            const float v1 = vt[(q4 * 4 + 1) * 64];
            const float v2 = vt[(q4 * 4 + 2) * 64];
            const float v3 = vt[(q4 * 4 + 3) * 64];
            a0 += p0.x * v0 + p0.y * v1 + p0.z * v2 + p0.w * v3;
            a1 += p1.x * v0 + p1.y * v1 + p1.z * v2 + p1.w * v3;
            a2 += p2.x * v0 + p2.y * v1 + p2.z * v2 + p2.w * v3;
            a3 += p3.x * v0 + p3.y * v1 + p3.z * v2 + p3.w * v3;
        }
    }

    // ---- partials to LDS; in-block flash merge ----
    accs[w][0][lane] = a0;
    accs[w][1][lane] = a1;
    accs[w][2][lane] = a2;
    accs[w][3][lane] = a3;
    if (lane == 0) {
        mls[w][0][0] = m0; mls[w][0][1] = l0;
        mls[w][1][0] = m1; mls[w][1][1] = l1;
        mls[w][2][0] = m2; mls[w][2][1] = l2;
        mls[w][3][0] = m3; mls[w][3][1] = l3;
    }
    __syncthreads();

    // wave w merges row r0 + w over all 4 wave partials
    const int rr = r0 + w;
    float ms = -1e30f;
#pragma unroll
    for (int ww = 0; ww < 4; ++ww) ms = fmaxf(ms, mls[ww][w][0]);
    float num = 0.f, den = 0.f;
#pragma unroll
    for (int ww = 0; ww < 4; ++ww) {
        const float e = __expf(mls[ww][w][0] - ms);
        den += mls[ww][w][1] * e;
        num += accs[ww][w][lane] * e;
    }
    out[(size_t)(b * 512 + rr) * 64 + lane] = num / den;
}

// ---------------------------------------------------------------------------
extern "C" void kernel_launch(void* const* d_in, const int* in_sizes, int n_in,
                              void* d_out, int out_size, void* d_ws, size_t ws_size,
                              hipStream_t stream)
{
    const float* x   = (const float*)d_in[0];
    const float* pos = (const float*)d_in[1];
    const float* W1  = (const float*)d_in[2];
    const float* b1  = (const float*)d_in[3];
    const float* W2  = (const float*)d_in[4];
    const float* b2  = (const float*)d_in[5];  (void)b2;  // cancels in softmax
    const float* Wv  = (const float*)d_in[6];
    float* out = (float*)d_out;
    float* ws = (float*)d_ws;

    float* Aq  = ws;                 // B*T*C = 262144
    float* AkT = ws + 262144;        // B*C*T = 262144 (transposed)
    float* V   = ws + 524288;        // B*T*HS = 131072

    k_prep<<<dim3(256), dim3(640), 0, stream>>>(x, pos, W1, b1, Wv, Aq, AkT, V);
    k_fused<<<dim3(512), dim3(256), 0, stream>>>(Aq, AkT, V, W2, out);
}